// Round 1
// baseline (1332.046 us; speedup 1.0000x reference)
//
#include <hip/hip_runtime.h>
#include <math.h>

#define Lc 4
#define Bc 4
#define Tc 1024
#define TCc 1024
#define T1c 2048
#define Dc 384
#define DKc 256
#define FFc 1536
#define TTc 0.1f
#define EPSc 1e-5f

typedef unsigned short u16;
typedef __attribute__((ext_vector_type(8))) __bf16 bf16x8;
typedef __attribute__((ext_vector_type(4))) float f32x4;

__device__ inline u16 f2bf(float f) {
  union { float f; unsigned u; } x; x.f = f;
  unsigned r = x.u + 0x7fffu + ((x.u >> 16) & 1u);
  return (u16)(r >> 16);
}

// ---------------- elementwise fp32 -> bf16 ----------------
__global__ void cvt_bf16(const float* __restrict__ in, u16* __restrict__ out, long n) {
  long i = (long)blockIdx.x * 256 + threadIdx.x;
  long st = (long)gridDim.x * 256;
  for (; i < n; i += st) out[i] = f2bf(in[i]);
}

// ------- score_c[l][b] (TC,T1) fp32 -> scT[b] (T1,TC) bf16 -------
__global__ __launch_bounds__(256) void transpose_cvt(const float* __restrict__ src,
                                                     u16* __restrict__ dst) {
  __shared__ float tile[32][33];
  const int b = blockIdx.z;
  const float* s = src + (long)b * TCc * T1c;
  u16* d = dst + (long)b * T1c * TCc;
  const int s0 = blockIdx.x * 32, c0 = blockIdx.y * 32;
  const int tx = threadIdx.x & 31, ty = threadIdx.x >> 5;
#pragma unroll
  for (int j = 0; j < 4; ++j)
    tile[ty + j * 8][tx] = s[(long)(c0 + ty + j * 8) * T1c + s0 + tx];
  __syncthreads();
#pragma unroll
  for (int j = 0; j < 4; ++j)
    d[(long)(s0 + ty + j * 8) * TCc + c0 + tx] = f2bf(tile[tx][ty + j * 8]);
}

// ---------------- generic bf16 GEMM: C = alpha*(A.B^T) + bias ----------------
// A: (M,K) bf16 row-major, B: (N,K) bf16 row-major. Both K-contiguous.
// Grid: (N/128, M/128, batch).  BIAS_MODE: 0 none, 1 per-col(n), 2 per-row(m)
template<int BIAS_MODE, int RELU, int OUT_BF16>
__global__ __launch_bounds__(256) void gemm_bt(
    const u16* __restrict__ A, const u16* __restrict__ B,
    void* __restrict__ C, const float* __restrict__ bias,
    float alpha, int N, int K, long sA, long sB, long sC)
{
  __shared__ __attribute__((aligned(16))) u16 As[128 * 32];
  __shared__ __attribute__((aligned(16))) u16 Bs[128 * 32];
  const int bz = blockIdx.z;
  const u16* Ab = A + (long)bz * sA;
  const u16* Bb = B + (long)bz * sB;
  const long tm = (long)blockIdx.y * 128;
  const long tn = (long)blockIdx.x * 128;
  const int tid = threadIdx.x;
  const int lane = tid & 63, wv = tid >> 6;
  const int wm = (wv >> 1) * 64, wn = (wv & 1) * 64;
  const int q = lane >> 4, r = lane & 15;
  const int ldr = lane >> 2;        // row within 16-row group
  const int ldc = (lane & 3) * 8;   // ushort offset within row (16B per lane)

  const f32x4 zero4 = {0.0f, 0.0f, 0.0f, 0.0f};
  f32x4 acc[4][4];
#pragma unroll
  for (int i = 0; i < 4; ++i)
#pragma unroll
    for (int j = 0; j < 4; ++j) acc[i][j] = zero4;

  for (int kt = 0; kt < K; kt += 32) {
    // stage 128x32 A-tile and B-tile via async global->LDS, 16B/lane
#pragma unroll
    for (int j = 0; j < 2; ++j) {
      const int rowo = wv * 32 + j * 16;
      const u16* ga = Ab + (tm + rowo + ldr) * (long)K + kt + ldc;
      __builtin_amdgcn_global_load_lds(
          (const __attribute__((address_space(1))) void*)ga,
          (__attribute__((address_space(3))) void*)(As + rowo * 32), 16, 0, 0);
      const u16* gb = Bb + (tn + rowo + ldr) * (long)K + kt + ldc;
      __builtin_amdgcn_global_load_lds(
          (const __attribute__((address_space(1))) void*)gb,
          (__attribute__((address_space(3))) void*)(Bs + rowo * 32), 16, 0, 0);
    }
    __syncthreads();

    bf16x8 af[4], bfr[4];
#pragma unroll
    for (int i = 0; i < 4; ++i) {
      af[i]  = *(const bf16x8*)(As + (wm + i * 16 + r) * 32 + q * 8);
      bfr[i] = *(const bf16x8*)(Bs + (wn + i * 16 + r) * 32 + q * 8);
    }
#pragma unroll
    for (int i = 0; i < 4; ++i)
#pragma unroll
      for (int j = 0; j < 4; ++j)
        acc[i][j] = __builtin_amdgcn_mfma_f32_16x16x32_bf16(af[i], bfr[j], acc[i][j], 0, 0, 0);
    __syncthreads();
  }

  // epilogue: D layout col=lane&15, row=(lane>>4)*4+reg  [measured m89/m91]
#pragma unroll
  for (int i = 0; i < 4; ++i)
#pragma unroll
    for (int j = 0; j < 4; ++j)
#pragma unroll
      for (int v = 0; v < 4; ++v) {
        long row = tm + wm + i * 16 + q * 4 + v;
        long col = tn + wn + j * 16 + r;
        float val = acc[i][j][v] * alpha;
        if (BIAS_MODE == 1) val += bias[col];
        if (BIAS_MODE == 2) val += bias[row];
        if (RELU) val = fmaxf(val, 0.0f);
        long idx = (long)bz * sC + row * (long)N + col;
        if (OUT_BF16) ((u16*)C)[idx] = f2bf(val);
        else          ((float*)C)[idx] = val;
      }
}

// -------- blended = TT*softmax(mixed) + (1-TT)*softmax(att), rows of T1 --------
__global__ __launch_bounds__(256) void blend_softmax(
    const float* __restrict__ att, const float* __restrict__ mixed,
    u16* __restrict__ out)
{
  const long row = blockIdx.x;
  const int tid = threadIdx.x;
  const float* ar = att + row * T1c;
  const float* mr = mixed + row * T1c;
  float a[8], m[8];
#pragma unroll
  for (int i = 0; i < 8; ++i) { a[i] = ar[tid + i * 256]; m[i] = mr[tid + i * 256]; }
  float amax = a[0], mmax = m[0];
#pragma unroll
  for (int i = 1; i < 8; ++i) { amax = fmaxf(amax, a[i]); mmax = fmaxf(mmax, m[i]); }
#pragma unroll
  for (int off = 32; off > 0; off >>= 1) {
    amax = fmaxf(amax, __shfl_xor(amax, off));
    mmax = fmaxf(mmax, __shfl_xor(mmax, off));
  }
  __shared__ float red[8];
  const int lane = tid & 63, wv = tid >> 6;
  if (lane == 0) { red[wv] = amax; red[4 + wv] = mmax; }
  __syncthreads();
  amax = fmaxf(fmaxf(red[0], red[1]), fmaxf(red[2], red[3]));
  mmax = fmaxf(fmaxf(red[4], red[5]), fmaxf(red[6], red[7]));
  __syncthreads();
  float asum = 0.f, msum = 0.f;
#pragma unroll
  for (int i = 0; i < 8; ++i) {
    a[i] = __expf(a[i] - amax); asum += a[i];
    m[i] = __expf(m[i] - mmax); msum += m[i];
  }
#pragma unroll
  for (int off = 32; off > 0; off >>= 1) {
    asum += __shfl_xor(asum, off);
    msum += __shfl_xor(msum, off);
  }
  if (lane == 0) { red[wv] = asum; red[4 + wv] = msum; }
  __syncthreads();
  asum = red[0] + red[1] + red[2] + red[3];
  msum = red[4] + red[5] + red[6] + red[7];
  const float ca = (1.0f - TTc) / asum, cm = TTc / msum;
#pragma unroll
  for (int i = 0; i < 8; ++i)
    out[row * T1c + tid + i * 256] = f2bf(a[i] * ca + m[i] * cm);
}

// -------- x = LN(xin + z) ; writes fp32 x and bf16 x --------
__global__ __launch_bounds__(384) void add_ln(
    const float* __restrict__ xin, const float* __restrict__ z,
    const float* __restrict__ g, const float* __restrict__ be,
    float* __restrict__ xout, u16* __restrict__ xbf)
{
  const long row = blockIdx.x;
  const int d = threadIdx.x;
  float v = xin[row * Dc + d] + z[row * Dc + d];
  float s = v, s2 = v * v;
#pragma unroll
  for (int off = 32; off > 0; off >>= 1) {
    s  += __shfl_xor(s, off);
    s2 += __shfl_xor(s2, off);
  }
  __shared__ float red[12];
  const int lane = d & 63, wv = d >> 6;
  if (lane == 0) { red[wv] = s; red[6 + wv] = s2; }
  __syncthreads();
  float S = 0.f, S2 = 0.f;
#pragma unroll
  for (int w = 0; w < 6; ++w) { S += red[w]; S2 += red[6 + w]; }
  const float mean = S * (1.0f / Dc);
  const float var  = S2 * (1.0f / Dc) - mean * mean;
  const float rstd = rsqrtf(var + EPSc);
  const float y = (v - mean) * rstd * g[d] + be[d];
  xout[row * Dc + d] = y;
  xbf[row * Dc + d] = f2bf(y);
}

extern "C" void kernel_launch(void* const* d_in, const int* in_sizes, int n_in,
                              void* d_out, int out_size, void* d_ws, size_t ws_size,
                              hipStream_t stream)
{
  const float* tgt     = (const float*)d_in[0];
  const float* memory  = (const float*)d_in[1];
  const float* score_c = (const float*)d_in[2];
  const float* out_c   = (const float*)d_in[3];
  const float* Wq  = (const float*)d_in[4];  const float* bq  = (const float*)d_in[5];
  const float* Wk  = (const float*)d_in[6];  const float* bk  = (const float*)d_in[7];
  const float* Wv  = (const float*)d_in[8];  const float* bv  = (const float*)d_in[9];
  const float* Wkn = (const float*)d_in[10]; const float* bkn = (const float*)d_in[11];
  const float* Wun = (const float*)d_in[12]; const float* bun = (const float*)d_in[13];
  const float* W1  = (const float*)d_in[14]; const float* b1  = (const float*)d_in[15];
  const float* W2  = (const float*)d_in[16]; const float* b2  = (const float*)d_in[17];
  const float* g1  = (const float*)d_in[18]; const float* be1 = (const float*)d_in[19];
  const float* g2  = (const float*)d_in[20]; const float* be2 = (const float*)d_in[21];
  (void)in_sizes; (void)n_in; (void)out_size;

  char* p = (char*)d_ws;
  auto alloc = [&](size_t b) { char* r = p; p += (b + 255) & ~(size_t)255; return r; };

  u16* wq_bf  = (u16*)alloc((size_t)Lc * Dc * Dc * 2);
  u16* wk_bf  = (u16*)alloc((size_t)Lc * Dc * DKc * 2);
  u16* wv_bf  = (u16*)alloc((size_t)Lc * Dc * DKc * 2);
  u16* wkn_bf = (u16*)alloc((size_t)Lc * Dc * Dc * 2);
  u16* wun_bf = (u16*)alloc((size_t)Lc * Dc * Dc * 2);
  u16* w1_bf  = (u16*)alloc((size_t)Lc * FFc * Dc * 2);
  u16* w2_bf  = (u16*)alloc((size_t)Lc * Dc * FFc * 2);
  u16* mem_bf = (u16*)alloc((size_t)Bc * T1c * DKc * 2);
  u16* outc_bf= (u16*)alloc((size_t)Lc * Bc * TCc * Dc * 2);
  u16* x_bf   = (u16*)alloc((size_t)Bc * Tc * Dc * 2);
  float* xbuf = (float*)alloc((size_t)Bc * Tc * Dc * 4);
  u16* q_bf   = (u16*)alloc((size_t)Bc * Tc * Dc * 2);
  u16* unk_bf = (u16*)alloc((size_t)Bc * Tc * Dc * 2);
  u16* k_bf   = (u16*)alloc((size_t)Bc * T1c * Dc * 2);   // contiguous with vT_bf
  u16* vT_bf  = (u16*)alloc((size_t)Bc * Dc * T1c * 2);
  u16* kno_bf = (u16*)alloc((size_t)Bc * TCc * Dc * 2);
  u16* s1_bf  = (u16*)alloc((size_t)Bc * Tc * TCc * 2);
  u16* scT    = (u16*)alloc((size_t)Bc * T1c * TCc * 2);  // aliased as blended
  float* att  = (float*)alloc((size_t)Bc * Tc * T1c * 4);
  float* mixed= (float*)alloc((size_t)Bc * Tc * T1c * 4);
  float* zbuf = (float*)alloc((size_t)Bc * Tc * Dc * 4);
  u16* h_bf   = k_bf;   // alias: spans k_bf + vT_bf (12.58 MB), lifetimes disjoint
  u16* blended= scT;    // alias: scT consumed (mixed GEMM) before blended written

  if ((size_t)(p - (char*)d_ws) > ws_size) return;  // fail loudly (poisoned out)

  auto cvt = [&](const float* s, u16* d, long n) {
    int blocks = (int)((n + 255) / 256); if (blocks > 4096) blocks = 4096;
    cvt_bf16<<<blocks, 256, 0, stream>>>(s, d, n);
  };
  cvt(Wq,  wq_bf,  (long)Lc * Dc * Dc);
  cvt(Wk,  wk_bf,  (long)Lc * Dc * DKc);
  cvt(Wv,  wv_bf,  (long)Lc * Dc * DKc);
  cvt(Wkn, wkn_bf, (long)Lc * Dc * Dc);
  cvt(Wun, wun_bf, (long)Lc * Dc * Dc);
  cvt(W1,  w1_bf,  (long)Lc * FFc * Dc);
  cvt(W2,  w2_bf,  (long)Lc * Dc * FFc);
  cvt(memory, mem_bf, (long)Bc * T1c * DKc);
  cvt(out_c, outc_bf, (long)Lc * Bc * TCc * Dc);
  cvt(tgt, x_bf, (long)Bc * Tc * Dc);

  const float scale = 1.0f / sqrtf((float)Dc);

  for (int l = 0; l < Lc; ++l) {
    // score_c[l] -> bf16 transposed (T1,TC)
    transpose_cvt<<<dim3(T1c / 32, TCc / 32, Bc), 256, 0, stream>>>(
        score_c + (long)l * Bc * TCc * T1c, scT);
    // q = x.Wq^T + bq   (4096x384, K=384)
    gemm_bt<1,0,1><<<dim3(Dc/128, (Bc*Tc)/128, 1), 256, 0, stream>>>(
        x_bf, wq_bf + (long)l*Dc*Dc, q_bf, bq + l*Dc, 1.0f, Dc, Dc, 0, 0, 0);
    // unk = x.Wun^T + bun
    gemm_bt<1,0,1><<<dim3(Dc/128, (Bc*Tc)/128, 1), 256, 0, stream>>>(
        x_bf, wun_bf + (long)l*Dc*Dc, unk_bf, bun + l*Dc, 1.0f, Dc, Dc, 0, 0, 0);
    // k = memory.Wk^T + bk   (8192x384, K=256)
    gemm_bt<1,0,1><<<dim3(Dc/128, (Bc*T1c)/128, 1), 256, 0, stream>>>(
        mem_bf, wk_bf + (long)l*Dc*DKc, k_bf, bk + l*Dc, 1.0f, Dc, DKc, 0, 0, 0);
    // vT[b] = (Wv.memory[b]^T) + bv(row)   (384x2048, K=256), batch B
    gemm_bt<2,0,1><<<dim3(T1c/128, Dc/128, Bc), 256, 0, stream>>>(
        wv_bf + (long)l*Dc*DKc, mem_bf, vT_bf, bv + l*Dc, 1.0f,
        T1c, DKc, 0, (long)T1c*DKc, (long)Dc*T1c);
    // att[b] = scale * q[b].k[b]^T  (1024x2048, K=384) fp32
    gemm_bt<0,0,0><<<dim3(T1c/128, Tc/128, Bc), 256, 0, stream>>>(
        q_bf, k_bf, att, nullptr, scale, T1c, Dc,
        (long)Tc*Dc, (long)T1c*Dc, (long)Tc*T1c);
    // kno = out_c[l].Wkn^T + bkn  (4096x384, K=384)
    gemm_bt<1,0,1><<<dim3(Dc/128, (Bc*TCc)/128, 1), 256, 0, stream>>>(
        outc_bf + (long)l*Bc*TCc*Dc, wkn_bf + (long)l*Dc*Dc, kno_bf,
        bkn + l*Dc, 1.0f, Dc, Dc, 0, 0, 0);
    // score1[b] = scale * unk[b].kno[b]^T  (1024x1024, K=384) bf16
    gemm_bt<0,0,1><<<dim3(TCc/128, Tc/128, Bc), 256, 0, stream>>>(
        unk_bf, kno_bf, s1_bf, nullptr, scale, TCc, Dc,
        (long)Tc*Dc, (long)TCc*Dc, (long)Tc*TCc);
    // mixed[b] = score1[b].scT[b]^T  (1024x2048, K=1024) fp32
    gemm_bt<0,0,0><<<dim3(T1c/128, Tc/128, Bc), 256, 0, stream>>>(
        s1_bf, scT, mixed, nullptr, 1.0f, T1c, TCc,
        (long)Tc*TCc, (long)T1c*TCc, (long)Tc*T1c);
    // blended = TT*softmax(mixed) + (1-TT)*softmax(att)  -> bf16 (aliases scT)
    blend_softmax<<<Bc*Tc, 256, 0, stream>>>(att, mixed, blended);
    // z[b] = blended[b].vT[b]^T  (1024x384, K=2048) fp32
    gemm_bt<0,0,0><<<dim3(Dc/128, Tc/128, Bc), 256, 0, stream>>>(
        blended, vT_bf, zbuf, nullptr, 1.0f, Dc, T1c,
        (long)Tc*T1c, (long)Dc*T1c, (long)Tc*Dc);
    // x = LN(x + z)
    add_ln<<<Bc*Tc, Dc, 0, stream>>>(
        (l == 0) ? tgt : xbuf, zbuf, g1 + l*Dc, be1 + l*Dc, xbuf, x_bf);
    // h = relu(x.W1^T + b1)  (4096x1536, K=384) bf16  (aliases k_bf+vT_bf)
    gemm_bt<1,1,1><<<dim3(FFc/128, (Bc*Tc)/128, 1), 256, 0, stream>>>(
        x_bf, w1_bf + (long)l*FFc*Dc, h_bf, b1 + l*FFc, 1.0f, FFc, Dc, 0, 0, 0);
    // y2 = h.W2^T + b2  (4096x384, K=1536) fp32 (reuse zbuf)
    gemm_bt<1,0,0><<<dim3(Dc/128, (Bc*Tc)/128, 1), 256, 0, stream>>>(
        h_bf, w2_bf + (long)l*Dc*FFc, zbuf, b2 + l*Dc, 1.0f, Dc, FFc, 0, 0, 0);
    // x = LN(x + y2) ; last layer writes d_out
    add_ln<<<Bc*Tc, Dc, 0, stream>>>(
        xbuf, zbuf, g2 + l*Dc, be2 + l*Dc,
        (l == Lc - 1) ? (float*)d_out : xbuf, x_bf);
  }
}